// Round 1
// baseline (312.451 us; speedup 1.0000x reference)
//
#include <hip/hip_runtime.h>
#include <hip/hip_bf16.h>
#include <hip/hip_fp16.h>
#include <stdint.h>

// Problem constants
#define B_ 32
#define T_ 2048
#define D_ 512
#define U_ 512
#define M_ (B_ * T_)   // 65536 rows of the flattened GEMM

// GEMM tiling
#define BM 64
#define BK 32
#define AP 8            // sA pad in halves -> row stride 40 halves = 80 B (16B-aligned)
#define MAXC 4          // exact-rescore candidates per batch

typedef _Float16 half8  __attribute__((ext_vector_type(8)));
typedef _Float16 half4_t __attribute__((ext_vector_type(4)));
typedef float   floatx4 __attribute__((ext_vector_type(4)));

// fast tanh: tanh(x) = sign(x) * (1 - 2/(e^{2|x|}+1)); |err| ~ few ulp, fine vs 2% gate
__device__ __forceinline__ float tanh_fast(float x) {
    float ax = fabsf(x);
    float e  = __expf(2.0f * ax);
    float t  = 1.0f - 2.0f / (e + 1.0f);
    return copysignf(t, x);
}

// async global->LDS, 16B per lane. LDS dest is wave-uniform base + lane*16.
__device__ __forceinline__ void gld_lds16(const void* gsrc, void* lds_dst) {
    typedef __attribute__((address_space(1))) const char gch;
    typedef __attribute__((address_space(3))) char lch;
    // generic LDS ptr = aperture(hi32)|offset(lo32); truncation to 32b yields LDS offset
    __builtin_amdgcn_global_load_lds((const gch*)(uintptr_t)gsrc,
                                     (lch*)(uint32_t)(uintptr_t)lds_dst,
                                     16, 0, 0);
}

// ---------------- k0: W1 [K][N] fp32 -> W1T [N][K] fp16 ----------------
__global__ __launch_bounds__(256)
void k_transpose_w1(const float* __restrict__ W1, _Float16* __restrict__ W1T) {
    __shared__ float tile[64][65];
    const int bx = blockIdx.x & 7;    // k-tile
    const int by = blockIdx.x >> 3;   // n-tile
    const int k0 = bx * 64, n0 = by * 64;
    const int tx = threadIdx.x & 63;
    const int ty = threadIdx.x >> 6;  // 0..3
#pragma unroll
    for (int i = 0; i < 16; ++i) {
        int r = ty * 16 + i;
        tile[r][tx] = W1[(size_t)(k0 + r) * U_ + n0 + tx];
    }
    __syncthreads();
#pragma unroll
    for (int i = 0; i < 16; ++i) {
        int r = ty * 16 + i;
        W1T[(size_t)(n0 + r) * D_ + k0 + tx] = (_Float16)tile[tx][r];
    }
}

// ---------------- k1: w2q[b][u] = query[b] @ W2, exact fp32 ----------------
__global__ __launch_bounds__(256)
void k_w2q(const float* __restrict__ query, const float* __restrict__ W2,
           float* __restrict__ w2q) {
    __shared__ float sq[D_];
    const int b = blockIdx.x;
    const int tid = threadIdx.x;
    sq[tid]       = query[b * D_ + tid];
    sq[tid + 256] = query[b * D_ + tid + 256];
    __syncthreads();
#pragma unroll
    for (int j = 0; j < 2; ++j) {
        const int n = tid + j * 256;
        float acc = 0.f;
#pragma unroll 16
        for (int d = 0; d < D_; ++d)
            acc = fmaf(sq[d], W2[(size_t)d * U_ + n], acc);
        w2q[b * U_ + n] = acc;
    }
}

// ---------------- k2: fused GEMM + tanh + V-dot -> u[b,t] ----------------
// block: 512 thr (8 waves), tile BM=64 x BN=512(full) x BK=32, fp16 MFMA 16x16x32
__global__ __launch_bounds__(512)
void k_gemm_u(const float* __restrict__ value,
              const _Float16* __restrict__ W1T,   // [N=512][K=512] fp16
              const float* __restrict__ w2q,      // [32][512]
              const float* __restrict__ Vv,       // [512]
              float* __restrict__ u_out) {        // [65536]
    __shared__ __align__(16) _Float16 sA[BM * (BK + AP)]; // [64][40], 5120 B
    __shared__ __align__(16) _Float16 sB[U_ * BK];        // [512][32] n-major, 32768 B
    __shared__ float sW2q[U_];
    __shared__ float sV[U_];
    __shared__ float sRed[8][BM];

    const int tid  = threadIdx.x;
    const int wave = tid >> 6;
    const int lane = tid & 63;
    const int l15  = lane & 15;
    const int lg   = lane >> 4;          // 0..3
    const int m0   = blockIdx.x * BM;
    const int b    = m0 >> 11;           // 2048 rows per batch; BM divides 2048

    sW2q[tid] = w2q[b * U_ + tid];
    sV[tid]   = Vv[tid];

    floatx4 acc[4][4];
    const floatx4 zero4 = {0.f, 0.f, 0.f, 0.f};
#pragma unroll
    for (int i = 0; i < 4; ++i)
#pragma unroll
        for (int j = 0; j < 4; ++j) acc[i][j] = zero4;

    // A staging: each thread loads one float4 of value and writes 4 halves
    const int ar = tid >> 3;             // 0..63
    const int ac = (tid & 7) * 4;        // 0..28
    const float* aptr = value + (size_t)(m0 + ar) * D_ + ac;

    // B staging via global_load_lds: inst = wave*4+jj; n = inst*16 + (lane>>2)
    const int bn = lane >> 2;            // 0..15
    const int bk = (lane & 3) * 8;       // 0,8,16,24 halves

    for (int it = 0; it < 16; ++it) {
        const int k0 = it * BK;
        __syncthreads();   // protect LDS vs previous iter's reads
        {   // stage A (fp32 -> fp16)
            const floatx4 v4 = *(const floatx4*)(aptr + k0);
            half4_t h;
            h[0] = (_Float16)v4[0]; h[1] = (_Float16)v4[1];
            h[2] = (_Float16)v4[2]; h[3] = (_Float16)v4[3];
            *(half4_t*)(&sA[ar * (BK + AP) + ac]) = h;
        }
#pragma unroll
        for (int jj = 0; jj < 4; ++jj) {  // stage B (async direct-to-LDS)
            const int inst = wave * 4 + jj;
            const int n = inst * 16 + bn;
            gld_lds16(W1T + (size_t)n * D_ + k0 + bk, (void*)(sB + inst * 512));
        }
        __syncthreads();  // full vmcnt/lgkm drain before compute

        half8 af[4], bf[4];
#pragma unroll
        for (int mi = 0; mi < 4; ++mi)
            af[mi] = *(const half8*)(&sA[(mi * 16 + l15) * (BK + AP) + lg * 8]);
#pragma unroll
        for (int ni = 0; ni < 4; ++ni) {
            const int n = wave * 64 + ni * 16 + l15;
            bf[ni] = *(const half8*)(&sB[n * BK + lg * 8]);
        }
#pragma unroll
        for (int ni = 0; ni < 4; ++ni)
#pragma unroll
            for (int mi = 0; mi < 4; ++mi)
                acc[mi][ni] = __builtin_amdgcn_mfma_f32_16x16x32_f16(
                    af[mi], bf[ni], acc[mi][ni], 0, 0, 0);
    }

    // epilogue: u contribution = sum_n V[n] * tanh(C[m][n] + w2q[b][n])
    float ps[4][4];
#pragma unroll
    for (int mi = 0; mi < 4; ++mi)
#pragma unroll
        for (int j = 0; j < 4; ++j) ps[mi][j] = 0.f;

#pragma unroll
    for (int ni = 0; ni < 4; ++ni) {
        const int n = wave * 64 + ni * 16 + l15;   // C/D: col = lane&15
        const float w2 = sW2q[n];
        const float vv = sV[n];
#pragma unroll
        for (int mi = 0; mi < 4; ++mi)
#pragma unroll
            for (int j = 0; j < 4; ++j)
                ps[mi][j] += vv * tanh_fast(acc[mi][ni][j] + w2);
    }
    // reduce across the 16 column-lanes (xor masks < 16 stay in-group)
#pragma unroll
    for (int off = 1; off < 16; off <<= 1)
#pragma unroll
        for (int mi = 0; mi < 4; ++mi)
#pragma unroll
            for (int j = 0; j < 4; ++j)
                ps[mi][j] += __shfl_xor(ps[mi][j], off, 64);

    if (l15 == 0) {
#pragma unroll
        for (int mi = 0; mi < 4; ++mi)
#pragma unroll
            for (int j = 0; j < 4; ++j)
                sRed[wave][mi * 16 + lg * 4 + j] = ps[mi][j];  // row = (lane>>4)*4 + reg
    }
    __syncthreads();
    if (tid < BM) {
        float s = 0.f;
#pragma unroll
        for (int w = 0; w < 8; ++w) s += sRed[w][tid];
        u_out[m0 + tid] = s;
    }
}

// ---------------- k3a: per-batch softmax + top-4 candidate selection ----------------
__global__ __launch_bounds__(256)
void k_softmax_top(const float* __restrict__ u, const int* __restrict__ mask,
                   float* __restrict__ a_out, int* __restrict__ cand_t) {
    __shared__ float sx[T_];
    __shared__ float rv[4];
    __shared__ int   ri[4];
    __shared__ float s_scalar;

    const int b = blockIdx.x;
    const int tid = threadIdx.x;
    const int wave = tid >> 6, lane = tid & 63;

#pragma unroll
    for (int i = 0; i < 8; ++i) {
        const int t = tid * 8 + i;
        float x = u[b * T_ + t];
        if (mask[b * T_ + t] == 0) x = -1e20f;  // == ref's u + (1-m)*(-1e20) in fp32
        sx[t] = x;
    }
    __syncthreads();

    for (int r = 0; r < MAXC; ++r) {
        float v = -INFINITY; int vi = 0;
#pragma unroll
        for (int i = 0; i < 8; ++i) {          // ascending t; '>' keeps first occurrence
            const int t = tid * 8 + i;
            const float x = sx[t];
            if (x > v) { v = x; vi = t; }
        }
        for (int off = 32; off > 0; off >>= 1) {
            const float ov = __shfl_down(v, off, 64);
            const int   oi = __shfl_down(vi, off, 64);
            if (ov > v || (ov == v && oi < vi)) { v = ov; vi = oi; }
        }
        if (lane == 0) { rv[wave] = v; ri[wave] = vi; }
        __syncthreads();
        if (tid == 0) {
            float bv = rv[0]; int bi = ri[0];
            for (int w = 1; w < 4; ++w)
                if (rv[w] > bv || (rv[w] == bv && ri[w] < bi)) { bv = rv[w]; bi = ri[w]; }
            cand_t[b * MAXC + r] = bi;
            if (r == 0) s_scalar = bv;          // global max for softmax
            sx[bi] = -INFINITY;                 // exclude for next round
        }
        __syncthreads();
    }
    const float mx = s_scalar;

    // softmax (reload x: sx was clobbered for the 4 picked entries)
    float zloc = 0.f;
    float evals[8];
#pragma unroll
    for (int i = 0; i < 8; ++i) {
        const int t = tid * 8 + i;
        float x = u[b * T_ + t];
        if (mask[b * T_ + t] == 0) x = -1e20f;
        const float e = __expf(x - mx);
        evals[i] = e;
        zloc += e;
    }
    for (int off = 32; off > 0; off >>= 1) zloc += __shfl_down(zloc, off, 64);
    if (lane == 0) rv[wave] = zloc;
    __syncthreads();
    if (tid == 0) s_scalar = 1.0f / (rv[0] + rv[1] + rv[2] + rv[3]);
    __syncthreads();
    const float rz = s_scalar;
#pragma unroll
    for (int i = 0; i < 8; ++i) {
        const int t = tid * 8 + i;
        a_out[b * T_ + t] = evals[i] * rz;
    }
}

// ---------------- k3b: exact fp32 rescore of candidates ----------------
__global__ __launch_bounds__(256)
void k_rescore(const float* __restrict__ value, const float* __restrict__ W1,
               const float* __restrict__ w2q, const float* __restrict__ Vv,
               const int* __restrict__ mask, const int* __restrict__ cand_t,
               float* __restrict__ cand_score) {
    __shared__ float vrow[D_];
    __shared__ float rsum[4];
    const int b  = blockIdx.x >> 2;
    const int ci = blockIdx.x & 3;
    const int t  = cand_t[b * MAXC + ci];
    const int tid = threadIdx.x;
    const int wave = tid >> 6, lane = tid & 63;
    vrow[tid]       = value[((size_t)b * T_ + t) * D_ + tid];
    vrow[tid + 256] = value[((size_t)b * T_ + t) * D_ + tid + 256];
    __syncthreads();
    float acc = 0.f;
#pragma unroll
    for (int j = 0; j < 2; ++j) {
        const int n = tid + j * 256;
        float dot = 0.f;
#pragma unroll 16
        for (int d = 0; d < D_; ++d)
            dot = fmaf(vrow[d], W1[(size_t)d * U_ + n], dot);
        acc += Vv[n] * tanhf(dot + w2q[b * U_ + n]);
    }
    for (int off = 32; off > 0; off >>= 1) acc += __shfl_down(acc, off, 64);
    if (lane == 0) rsum[wave] = acc;
    __syncthreads();
    if (tid == 0) {
        float s = rsum[0] + rsum[1] + rsum[2] + rsum[3];
        if (mask[b * T_ + t] == 0) s = -1e20f;  // belt & braces
        cand_score[b * MAXC + ci] = s;
    }
}

// ---------------- k3c: pick exact argmax among candidates, gather context ----------------
__global__ __launch_bounds__(128)
void k_finalize(const float* __restrict__ value, const int* __restrict__ cand_t,
                const float* __restrict__ cand_score, float* __restrict__ ctx_out) {
    __shared__ int s_t;
    const int b = blockIdx.x;
    const int tid = threadIdx.x;
    if (tid == 0) {
        float bv = cand_score[b * MAXC + 0]; int bt = cand_t[b * MAXC + 0];
        for (int i = 1; i < MAXC; ++i) {
            const float v = cand_score[b * MAXC + i];
            const int   t = cand_t[b * MAXC + i];
            if (v > bv || (v == bv && t < bt)) { bv = v; bt = t; }
        }
        s_t = bt;
    }
    __syncthreads();
    const int t = s_t;
    const floatx4* src = (const floatx4*)(value + ((size_t)b * T_ + t) * D_);
    floatx4* dst = (floatx4*)(ctx_out + b * D_);
    dst[tid] = src[tid];   // 128 thr * 16B = 512 floats
}

extern "C" void kernel_launch(void* const* d_in, const int* in_sizes, int n_in,
                              void* d_out, int out_size, void* d_ws, size_t ws_size,
                              hipStream_t stream) {
    const float* value = (const float*)d_in[0];   // [32,2048,512]
    const float* query = (const float*)d_in[1];   // [32,512]
    const int*   mask  = (const int*)d_in[2];     // [32,2048]
    const float* W1    = (const float*)d_in[3];   // [512,512]
    const float* W2    = (const float*)d_in[4];   // [512,512]
    const float* Vv    = (const float*)d_in[5];   // [512]

    // workspace map (~854 KB total)
    char* ws = (char*)d_ws;
    _Float16* W1T   = (_Float16*)ws;                      // 524288 B
    float*    w2q   = (float*)(ws + 524288);              // 65536 B
    float*    u_ws  = (float*)(ws + 524288 + 65536);      // 262144 B
    int*      candt = (int*)(ws + 851968);                // 512 B
    float*    cands = (float*)(ws + 852992);              // 512 B

    float* ctx_out = (float*)d_out;              // [32,512]
    float* a_out   = (float*)d_out + B_ * D_;    // [32,2048]

    hipLaunchKernelGGL(k_transpose_w1, dim3(64), dim3(256), 0, stream, W1, W1T);
    hipLaunchKernelGGL(k_w2q,          dim3(32), dim3(256), 0, stream, query, W2, w2q);
    hipLaunchKernelGGL(k_gemm_u,       dim3(M_ / BM), dim3(512), 0, stream,
                       value, W1T, w2q, Vv, u_ws);
    hipLaunchKernelGGL(k_softmax_top,  dim3(32), dim3(256), 0, stream,
                       u_ws, mask, a_out, candt);
    hipLaunchKernelGGL(k_rescore,      dim3(32 * MAXC), dim3(256), 0, stream,
                       value, W1, w2q, Vv, mask, candt, cands);
    hipLaunchKernelGGL(k_finalize,     dim3(32), dim3(128), 0, stream,
                       value, candt, cands, ctx_out);
}

// Round 2
// 306.935 us; speedup vs baseline: 1.0180x; 1.0180x over previous
//
#include <hip/hip_runtime.h>
#include <hip/hip_bf16.h>
#include <hip/hip_fp16.h>
#include <stdint.h>

// Problem constants
#define B_ 32
#define T_ 2048
#define D_ 512
#define U_ 512
#define M_ (B_ * T_)

// GEMM tiling: BM=64 rows/block, full-K A resident in LDS, BK=32 B-chunks dbuf'd
#define BM 64
#define BK 32
#define SAW 520          // sA row stride in halves (512 + 8 pad; 1040 B = 65*16, b128-aligned)
#define MAXC 4

typedef _Float16 half8  __attribute__((ext_vector_type(8)));
typedef float   floatx4 __attribute__((ext_vector_type(4)));

__device__ __forceinline__ float tanh_fast(float x) {
    float ax = fabsf(x);
    float e  = __expf(2.0f * ax);
    float t  = 1.0f - 2.0f / (e + 1.0f);
    return copysignf(t, x);
}

// async global->LDS, 16B per lane. LDS dest is wave-uniform base + lane*16.
__device__ __forceinline__ void gld_lds16(const void* gsrc, void* lds_dst) {
    typedef __attribute__((address_space(1))) const char gch;
    typedef __attribute__((address_space(3))) char lch;
    __builtin_amdgcn_global_load_lds((const gch*)(uintptr_t)gsrc,
                                     (lch*)(uint32_t)(uintptr_t)lds_dst,
                                     16, 0, 0);
}

// ---------------- k_prep: fused {W1 -> W1T fp16 transpose} + {w2q = query @ W2} ----
// blocks 0..63: transpose; blocks 64..191: w2q (32 b x 4 n-chunks)
__global__ __launch_bounds__(256)
void k_prep(const float* __restrict__ W1, const float* __restrict__ query,
            const float* __restrict__ W2, _Float16* __restrict__ W1T,
            float* __restrict__ w2q) {
    const int bid = blockIdx.x;
    const int tid = threadIdx.x;
    if (bid < 64) {
        __shared__ float tile[64][65];
        const int bx = bid & 7;          // k-tile
        const int by = bid >> 3;         // n-tile
        const int k0 = bx * 64, n0 = by * 64;
        const int tx = tid & 63;
        const int ty = tid >> 6;         // 0..3
#pragma unroll
        for (int i = 0; i < 16; ++i) {
            int r = ty * 16 + i;
            tile[r][tx] = W1[(size_t)(k0 + r) * U_ + n0 + tx];
        }
        __syncthreads();
#pragma unroll
        for (int i = 0; i < 16; ++i) {
            int r = ty * 16 + i;
            W1T[(size_t)(n0 + r) * D_ + k0 + tx] = (_Float16)tile[tx][r];
        }
    } else {
        __shared__ float sq[D_];
        __shared__ float part[128];
        const int id = bid - 64;
        const int b  = id >> 2;          // 0..31
        const int nq = id & 3;           // n-chunk of 128
        sq[tid]       = query[b * D_ + tid];
        sq[tid + 256] = query[b * D_ + tid + 256];
        __syncthreads();
        const int n  = nq * 128 + (tid & 127);
        const int dh = tid >> 7;         // 0/1 -> d-half
        float acc = 0.f;
        const int d0 = dh * 256;
#pragma unroll 16
        for (int d = d0; d < d0 + 256; ++d)
            acc = fmaf(sq[d], W2[(size_t)d * U_ + n], acc);
        if (dh == 1) part[tid & 127] = acc;
        __syncthreads();
        if (dh == 0) w2q[b * U_ + n] = acc + part[tid];
    }
}

// ---------------- k_gemm_u: fused GEMM + tanh + V-dot -> u[b,t] ----------------
// 512 thr (8 waves). A[64][512] fp16 staged ONCE to LDS; B chunks (512x32 fp16)
// double-buffered via global_load_lds issued one iteration ahead.
__global__ __launch_bounds__(512)
void k_gemm_u(const float* __restrict__ value,
              const _Float16* __restrict__ W1T,   // [N=512][K=512] fp16
              const float* __restrict__ w2q,      // [32][512]
              const float* __restrict__ Vv,       // [512]
              float* __restrict__ u_out) {        // [65536]
    __shared__ __align__(16) _Float16 sA[BM * SAW];      // 66,560 B
    __shared__ __align__(16) _Float16 sB[2][U_ * BK];    // 2 x 32,768 B
    __shared__ float sW2q[U_];
    __shared__ float sV[U_];
    __shared__ float sRed[8][BM];

    const int tid  = threadIdx.x;
    const int wave = tid >> 6;
    const int lane = tid & 63;
    const int l15  = lane & 15;
    const int lg   = lane >> 4;          // 0..3
    const int m0   = blockIdx.x * BM;
    const int b    = m0 >> 11;

    sW2q[tid] = w2q[b * U_ + tid];
    sV[tid]   = Vv[tid];

    // B-DMA lane mapping: n-local = lane>>2, k-offset = (lane&3)*8 halves
    const int bn  = lane >> 2;
    const int bk8 = (lane & 3) * 8;

    // issue B chunk 0 DMA immediately
#pragma unroll
    for (int jj = 0; jj < 4; ++jj) {
        const int inst = wave * 4 + jj;
        const int n = inst * 16 + bn;
        gld_lds16(W1T + (size_t)n * D_ + bk8, (void*)(&sB[0][inst * 512]));
    }

    // stage full-K A tile: wave w covers rows w*8..w*8+7; lane covers 8 cols
#pragma unroll
    for (int j = 0; j < 8; ++j) {
        const int row = wave * 8 + j;
        const float* src = value + (size_t)(m0 + row) * D_ + lane * 8;
        const floatx4 x0 = *(const floatx4*)(src);
        const floatx4 x1 = *(const floatx4*)(src + 4);
        half8 h;
        h[0] = (_Float16)x0[0]; h[1] = (_Float16)x0[1];
        h[2] = (_Float16)x0[2]; h[3] = (_Float16)x0[3];
        h[4] = (_Float16)x1[0]; h[5] = (_Float16)x1[1];
        h[6] = (_Float16)x1[2]; h[7] = (_Float16)x1[3];
        *(half8*)(&sA[row * SAW + lane * 8]) = h;
    }

    floatx4 acc[4][4];
    const floatx4 zero4 = {0.f, 0.f, 0.f, 0.f};
#pragma unroll
    for (int i = 0; i < 4; ++i)
#pragma unroll
        for (int j = 0; j < 4; ++j) acc[i][j] = zero4;

    __syncthreads();   // drains A stores + B(0) DMA

    for (int kk = 0; kk < 16; ++kk) {
        const int cur = kk & 1;
        if (kk < 15) {   // prefetch next B chunk into the other buffer
            const int k0n = (kk + 1) * BK;
#pragma unroll
            for (int jj = 0; jj < 4; ++jj) {
                const int inst = wave * 4 + jj;
                const int n = inst * 16 + bn;
                gld_lds16(W1T + (size_t)n * D_ + k0n + bk8,
                          (void*)(&sB[cur ^ 1][inst * 512]));
            }
        }
        half8 af[4], bf[4];
#pragma unroll
        for (int mi = 0; mi < 4; ++mi)
            af[mi] = *(const half8*)(&sA[(mi * 16 + l15) * SAW + kk * BK + lg * 8]);
#pragma unroll
        for (int ni = 0; ni < 4; ++ni) {
            const int n = wave * 64 + ni * 16 + l15;
            bf[ni] = *(const half8*)(&sB[cur][n * BK + lg * 8]);
        }
#pragma unroll
        for (int ni = 0; ni < 4; ++ni)
#pragma unroll
            for (int mi = 0; mi < 4; ++mi)
                acc[mi][ni] = __builtin_amdgcn_mfma_f32_16x16x32_f16(
                    af[mi], bf[ni], acc[mi][ni], 0, 0, 0);
        __syncthreads();   // waits next-B DMA (issued before compute) + buffer reuse
    }

    // epilogue: u contribution = sum_n V[n] * tanh(C[m][n] + w2q[b][n])
    float ps[4][4];
#pragma unroll
    for (int mi = 0; mi < 4; ++mi)
#pragma unroll
        for (int j = 0; j < 4; ++j) ps[mi][j] = 0.f;

#pragma unroll
    for (int ni = 0; ni < 4; ++ni) {
        const int n = wave * 64 + ni * 16 + l15;   // C/D: col = lane&15
        const float w2 = sW2q[n];
        const float vv = sV[n];
#pragma unroll
        for (int mi = 0; mi < 4; ++mi)
#pragma unroll
            for (int j = 0; j < 4; ++j)
                ps[mi][j] += vv * tanh_fast(acc[mi][ni][j] + w2);
    }
#pragma unroll
    for (int off = 1; off < 16; off <<= 1)
#pragma unroll
        for (int mi = 0; mi < 4; ++mi)
#pragma unroll
            for (int j = 0; j < 4; ++j)
                ps[mi][j] += __shfl_xor(ps[mi][j], off, 64);

    if (l15 == 0) {
#pragma unroll
        for (int mi = 0; mi < 4; ++mi)
#pragma unroll
            for (int j = 0; j < 4; ++j)
                sRed[wave][mi * 16 + lg * 4 + j] = ps[mi][j];  // row = (lane>>4)*4 + reg
    }
    __syncthreads();
    if (tid < BM) {
        float s = 0.f;
#pragma unroll
        for (int w = 0; w < 8; ++w) s += sRed[w][tid];
        u_out[m0 + tid] = s;
    }
}

// ---------------- k_post: softmax + top-4 + joint exact rescore + gather -------
__global__ __launch_bounds__(256)
void k_post(const float* __restrict__ u, const int* __restrict__ mask,
            const float* __restrict__ value, const float* __restrict__ W1,
            const float* __restrict__ w2q, const float* __restrict__ Vv,
            float* __restrict__ a_out, float* __restrict__ ctx_out) {
    __shared__ float sx[T_];
    __shared__ float rv[4];
    __shared__ int   ri[4];
    __shared__ float s_scalar;
    __shared__ int   s_cand[MAXC];
    __shared__ float s_score[MAXC];
    __shared__ __align__(16) float vrows[MAXC][D_];
    __shared__ int   s_t;

    const int b = blockIdx.x;
    const int tid = threadIdx.x;
    const int wave = tid >> 6, lane = tid & 63;

    // ---- load masked scores ----
#pragma unroll
    for (int i = 0; i < 8; ++i) {
        const int t = tid * 8 + i;
        float x = u[b * T_ + t];
        if (mask[b * T_ + t] == 0) x = -1e20f;
        sx[t] = x;
    }
    __syncthreads();

    // ---- top-4 selection (4 rounds) ----
    for (int r = 0; r < MAXC; ++r) {
        float v = -INFINITY; int vi = 0;
#pragma unroll
        for (int i = 0; i < 8; ++i) {
            const int t = tid * 8 + i;
            const float x = sx[t];
            if (x > v) { v = x; vi = t; }
        }
        for (int off = 32; off > 0; off >>= 1) {
            const float ov = __shfl_down(v, off, 64);
            const int   oi = __shfl_down(vi, off, 64);
            if (ov > v || (ov == v && oi < vi)) { v = ov; vi = oi; }
        }
        if (lane == 0) { rv[wave] = v; ri[wave] = vi; }
        __syncthreads();
        if (tid == 0) {
            float bv = rv[0]; int bi = ri[0];
            for (int w = 1; w < 4; ++w)
                if (rv[w] > bv || (rv[w] == bv && ri[w] < bi)) { bv = rv[w]; bi = ri[w]; }
            s_cand[r] = bi;
            if (r == 0) s_scalar = bv;
            sx[bi] = -INFINITY;
        }
        __syncthreads();
    }
    const float mx = s_scalar;

    // ---- softmax ----
    float zloc = 0.f;
    float evals[8];
#pragma unroll
    for (int i = 0; i < 8; ++i) {
        const int t = tid * 8 + i;
        float x = u[b * T_ + t];
        if (mask[b * T_ + t] == 0) x = -1e20f;
        const float e = __expf(x - mx);
        evals[i] = e;
        zloc += e;
    }
    for (int off = 32; off > 0; off >>= 1) zloc += __shfl_down(zloc, off, 64);
    if (lane == 0) rv[wave] = zloc;
    __syncthreads();
    if (tid == 0) s_scalar = 1.0f / (rv[0] + rv[1] + rv[2] + rv[3]);
    __syncthreads();
    const float rz = s_scalar;
#pragma unroll
    for (int i = 0; i < 8; ++i) {
        const int t = tid * 8 + i;
        a_out[b * T_ + t] = evals[i] * rz;
    }

    // ---- joint exact fp32 rescore of the 4 candidates (one pass over W1) ----
#pragma unroll
    for (int ci = 0; ci < MAXC; ++ci) {
        const int t = s_cand[ci];
        vrows[ci][tid]       = value[((size_t)b * T_ + t) * D_ + tid];
        vrows[ci][tid + 256] = value[((size_t)b * T_ + t) * D_ + tid + 256];
    }
    __syncthreads();

    float dots[2][MAXC];
#pragma unroll
    for (int j = 0; j < 2; ++j)
#pragma unroll
        for (int ci = 0; ci < MAXC; ++ci) dots[j][ci] = 0.f;

    for (int d4 = 0; d4 < D_; d4 += 4) {
        floatx4 vr[MAXC];
#pragma unroll
        for (int ci = 0; ci < MAXC; ++ci)
            vr[ci] = *(const floatx4*)(&vrows[ci][d4]);
#pragma unroll
        for (int k = 0; k < 4; ++k) {
            const float w0 = W1[(size_t)(d4 + k) * U_ + tid];
            const float w1 = W1[(size_t)(d4 + k) * U_ + tid + 256];
#pragma unroll
            for (int ci = 0; ci < MAXC; ++ci) {
                dots[0][ci] = fmaf(vr[ci][k], w0, dots[0][ci]);
                dots[1][ci] = fmaf(vr[ci][k], w1, dots[1][ci]);
            }
        }
    }
    // score_ci = sum_n V[n]*tanh(dots + w2q)
    float sc[MAXC];
#pragma unroll
    for (int ci = 0; ci < MAXC; ++ci) {
        const float n0v = Vv[tid]       * tanhf(dots[0][ci] + w2q[b * U_ + tid]);
        const float n1v = Vv[tid + 256] * tanhf(dots[1][ci] + w2q[b * U_ + tid + 256]);
        sc[ci] = n0v + n1v;
    }
#pragma unroll
    for (int ci = 0; ci < MAXC; ++ci)
        for (int off = 32; off > 0; off >>= 1)
            sc[ci] += __shfl_down(sc[ci], off, 64);
    if (lane == 0) {
#pragma unroll
        for (int ci = 0; ci < MAXC; ++ci) rv[ci * 0 + ci] = 0.f;  // placeholder no-op
    }
    // reduce 4 wave partials per candidate via LDS
    __syncthreads();
    if (lane == 0) {
#pragma unroll
        for (int ci = 0; ci < MAXC; ++ci)
            vrows[ci][wave] = sc[ci];   // reuse vrows row as scratch (4 floats)
    }
    __syncthreads();
    if (tid == 0) {
#pragma unroll
        for (int ci = 0; ci < MAXC; ++ci) {
            const int t = s_cand[ci];
            float s = vrows[ci][0] + vrows[ci][1] + vrows[ci][2] + vrows[ci][3];
            if (mask[b * T_ + t] == 0) s = -1e20f;
            s_score[ci] = s;
        }
        float bv = s_score[0]; int bt = s_cand[0];
        for (int i = 1; i < MAXC; ++i) {
            if (s_score[i] > bv || (s_score[i] == bv && s_cand[i] < bt)) {
                bv = s_score[i]; bt = s_cand[i];
            }
        }
        s_t = bt;
    }
    __syncthreads();

    // ---- gather context row ----
    const int t = s_t;
    ctx_out[b * D_ + tid]       = value[((size_t)b * T_ + t) * D_ + tid];
    ctx_out[b * D_ + tid + 256] = value[((size_t)b * T_ + t) * D_ + tid + 256];
}

extern "C" void kernel_launch(void* const* d_in, const int* in_sizes, int n_in,
                              void* d_out, int out_size, void* d_ws, size_t ws_size,
                              hipStream_t stream) {
    const float* value = (const float*)d_in[0];   // [32,2048,512]
    const float* query = (const float*)d_in[1];   // [32,512]
    const int*   mask  = (const int*)d_in[2];     // [32,2048]
    const float* W1    = (const float*)d_in[3];   // [512,512]
    const float* W2    = (const float*)d_in[4];   // [512,512]
    const float* Vv    = (const float*)d_in[5];   // [512]

    char* ws = (char*)d_ws;
    _Float16* W1T  = (_Float16*)ws;                    // 524,288 B
    float*    w2q  = (float*)(ws + 524288);            //  65,536 B
    float*    u_ws = (float*)(ws + 524288 + 65536);    // 262,144 B

    float* ctx_out = (float*)d_out;              // [32,512]
    float* a_out   = (float*)d_out + B_ * D_;    // [32,2048]

    hipLaunchKernelGGL(k_prep,   dim3(192), dim3(256), 0, stream,
                       W1, query, W2, W1T, w2q);
    hipLaunchKernelGGL(k_gemm_u, dim3(M_ / BM), dim3(512), 0, stream,
                       value, W1T, w2q, Vv, u_ws);
    hipLaunchKernelGGL(k_post,   dim3(32), dim3(256), 0, stream,
                       u_ws, mask, value, W1, w2q, Vv, a_out, ctx_out);
}

// Round 3
// 305.969 us; speedup vs baseline: 1.0212x; 1.0032x over previous
//
#include <hip/hip_runtime.h>
#include <hip/hip_bf16.h>
#include <hip/hip_fp16.h>
#include <stdint.h>

// Problem constants
#define B_ 32
#define T_ 2048
#define D_ 512
#define U_ 512
#define M_ (B_ * T_)

// GEMM tiling
#define BM 64
#define BK 32
#define SAW 40           // sA row stride in halves (32 + 8 pad; 80 B = 5*16B, b128-aligned)
#define MAXC 4

typedef _Float16 half8  __attribute__((ext_vector_type(8)));
typedef _Float16 half4_t __attribute__((ext_vector_type(4)));
typedef float   floatx4 __attribute__((ext_vector_type(4)));

__device__ __forceinline__ float tanh_fast(float x) {
    float ax = fabsf(x);
    float e  = __expf(2.0f * ax);
    float t  = 1.0f - 2.0f / (e + 1.0f);
    return copysignf(t, x);
}

// async global->LDS, 16B per lane. LDS dest is wave-uniform base + lane*16.
__device__ __forceinline__ void gld_lds16(const void* gsrc, void* lds_dst) {
    typedef __attribute__((address_space(1))) const char gch;
    typedef __attribute__((address_space(3))) char lch;
    __builtin_amdgcn_global_load_lds((const gch*)(uintptr_t)gsrc,
                                     (lch*)(uint32_t)(uintptr_t)lds_dst,
                                     16, 0, 0);
}

// ---------------- k_prep: fused {W1 -> W1T fp16 transpose} + {w2q = query @ W2} ----
__global__ __launch_bounds__(256)
void k_prep(const float* __restrict__ W1, const float* __restrict__ query,
            const float* __restrict__ W2, _Float16* __restrict__ W1T,
            float* __restrict__ w2q) {
    const int bid = blockIdx.x;
    const int tid = threadIdx.x;
    if (bid < 64) {
        __shared__ float tile[64][65];
        const int bx = bid & 7;          // k-tile
        const int by = bid >> 3;         // n-tile
        const int k0 = bx * 64, n0 = by * 64;
        const int tx = tid & 63;
        const int ty = tid >> 6;         // 0..3
#pragma unroll
        for (int i = 0; i < 16; ++i) {
            int r = ty * 16 + i;
            tile[r][tx] = W1[(size_t)(k0 + r) * U_ + n0 + tx];
        }
        __syncthreads();
#pragma unroll
        for (int i = 0; i < 16; ++i) {
            int r = ty * 16 + i;
            W1T[(size_t)(n0 + r) * D_ + k0 + tx] = (_Float16)tile[tx][r];
        }
    } else {
        __shared__ float sq[D_];
        __shared__ float part[128];
        const int id = bid - 64;
        const int b  = id >> 2;          // 0..31
        const int nq = id & 3;           // n-chunk of 128
        sq[tid]       = query[b * D_ + tid];
        sq[tid + 256] = query[b * D_ + tid + 256];
        __syncthreads();
        const int n  = nq * 128 + (tid & 127);
        const int dh = tid >> 7;         // 0/1 -> d-half
        float acc = 0.f;
        const int d0 = dh * 256;
#pragma unroll 16
        for (int d = d0; d < d0 + 256; ++d)
            acc = fmaf(sq[d], W2[(size_t)d * U_ + n], acc);
        if (dh == 1) part[tid & 127] = acc;
        __syncthreads();
        if (dh == 0) w2q[b * U_ + n] = acc + part[tid];
    }
}

// ---------------- k_gemm_u: fused GEMM + tanh + V-dot -> u[b,t] ----------------
// 512 thr (8 waves). Per-iter: A chunk prefetched depth-2 via registers (fp32->fp16
// cvt in-flight), B chunk double-buffered via global_load_lds with a bank-conflict-
// free cell swizzle. LDS 77.8 KB -> 2 blocks/CU.
__global__ __launch_bounds__(512, 4)
void k_gemm_u(const float* __restrict__ value,
              const _Float16* __restrict__ W1T,   // [N=512][K=512] fp16
              const float* __restrict__ w2q,      // [32][512]
              const float* __restrict__ Vv,       // [512]
              float* __restrict__ u_out) {        // [65536]
    __shared__ __align__(16) _Float16 sA[2][BM * SAW];   // 2 x 5,120 B
    __shared__ __align__(16) _Float16 sB[2][U_ * BK];    // 2 x 32,768 B
    __shared__ float sRed[8][BM];                        // 2,048 B

    const int tid  = threadIdx.x;
    const int wave = tid >> 6;
    const int lane = tid & 63;
    const int l15  = lane & 15;
    const int lg   = lane >> 4;          // 0..3
    const int m0   = blockIdx.x * BM;
    const int b    = m0 >> 11;

    // ---- B-DMA mapping: inst = wave*4+jj covers n in [inst*16, inst*16+16), full BK.
    // lane l fetches W1T[n = inst*16 + (l&15)][k0 + (l>>4)*8 .. +8) -> lands at cell l.
    // Read-back cell for (n_local, lg) = lg*16 + n_local  => frag reads hit 4-bank
    // stride (2-way, free) instead of 64 B stride (8-way).
    const int bnl  = l15;                // n_local fetched by this lane
    const int bhi8 = lg * 8;             // k-offset in halves

    // ---- A staging mapping: thread t loads value[m0 + (t>>3)][kk*32 + (t&7)*4 ..+4)
    const int ar = tid >> 3;             // 0..63
    const int ac = (tid & 7) * 4;        // 0..28
    const float* aptr = value + (size_t)(m0 + ar) * D_ + ac;

    floatx4 rA[2];

    // ---- prologue: chunks 0,1 in regs; write chunk 0; B0 DMA
    rA[0] = *(const floatx4*)(aptr);
    rA[1] = *(const floatx4*)(aptr + BK);
#pragma unroll
    for (int jj = 0; jj < 4; ++jj) {
        const int inst = wave * 4 + jj;
        const int n = inst * 16 + bnl;
        gld_lds16(W1T + (size_t)n * D_ + bhi8, (void*)(&sB[0][inst * 512]));
    }
    {
        half4_t h;
        h[0] = (_Float16)rA[0][0]; h[1] = (_Float16)rA[0][1];
        h[2] = (_Float16)rA[0][2]; h[3] = (_Float16)rA[0][3];
        *(half4_t*)(&sA[0][ar * SAW + ac]) = h;
    }

    floatx4 acc[4][4];
    const floatx4 zero4 = {0.f, 0.f, 0.f, 0.f};
#pragma unroll
    for (int i = 0; i < 4; ++i)
#pragma unroll
        for (int j = 0; j < 4; ++j) acc[i][j] = zero4;

    __syncthreads();   // drains sA[0] writes + B0 DMA

    for (int kk = 0; kk < 16; ++kk) {
        const int cur = kk & 1;
        // 1. prefetch B chunk kk+1 (L2-resident W1T)
        if (kk < 15) {
            const int k0n = (kk + 1) * BK;
#pragma unroll
            for (int jj = 0; jj < 4; ++jj) {
                const int inst = wave * 4 + jj;
                const int n = inst * 16 + bnl;
                gld_lds16(W1T + (size_t)n * D_ + k0n + bhi8,
                          (void*)(&sB[cur ^ 1][inst * 512]));
            }
        }
        // 2. issue A-load for chunk kk+2 (HBM; consumed 2 iters later)
        if (kk < 14) rA[cur] = *(const floatx4*)(aptr + (kk + 2) * BK);

        // 3. fragments + MFMA for chunk kk
        half8 af[4], bf[4];
#pragma unroll
        for (int mi = 0; mi < 4; ++mi)
            af[mi] = *(const half8*)(&sA[cur][(mi * 16 + l15) * SAW + lg * 8]);
#pragma unroll
        for (int ni = 0; ni < 4; ++ni) {
            const int inst = wave * 4 + ni;
            bf[ni] = *(const half8*)(&sB[cur][inst * 512 + (lg * 16 + l15) * 8]);
        }
#pragma unroll
        for (int ni = 0; ni < 4; ++ni)
#pragma unroll
            for (int mi = 0; mi < 4; ++mi)
                acc[mi][ni] = __builtin_amdgcn_mfma_f32_16x16x32_f16(
                    af[mi], bf[ni], acc[mi][ni], 0, 0, 0);

        // 4. cvt + LDS-write A chunk kk+1 (loaded at iter kk-1)
        if (kk < 15) {
            const floatx4 v4 = rA[cur ^ 1];
            half4_t h;
            h[0] = (_Float16)v4[0]; h[1] = (_Float16)v4[1];
            h[2] = (_Float16)v4[2]; h[3] = (_Float16)v4[3];
            *(half4_t*)(&sA[cur ^ 1][ar * SAW + ac]) = h;
        }
        __syncthreads();
    }

    // ---- epilogue: u contribution = sum_n V[n] * tanh(C[m][n] + w2q[b][n])
    float ps[4][4];
#pragma unroll
    for (int mi = 0; mi < 4; ++mi)
#pragma unroll
        for (int j = 0; j < 4; ++j) ps[mi][j] = 0.f;

#pragma unroll
    for (int ni = 0; ni < 4; ++ni) {
        const int n = wave * 64 + ni * 16 + l15;   // C/D: col = lane&15
        const float w2 = w2q[b * U_ + n];
        const float vv = Vv[n];
#pragma unroll
        for (int mi = 0; mi < 4; ++mi)
#pragma unroll
            for (int j = 0; j < 4; ++j)
                ps[mi][j] += vv * tanh_fast(acc[mi][ni][j] + w2);
    }
#pragma unroll
    for (int off = 1; off < 16; off <<= 1)
#pragma unroll
        for (int mi = 0; mi < 4; ++mi)
#pragma unroll
            for (int j = 0; j < 4; ++j)
                ps[mi][j] += __shfl_xor(ps[mi][j], off, 64);

    if (l15 == 0) {
#pragma unroll
        for (int mi = 0; mi < 4; ++mi)
#pragma unroll
            for (int j = 0; j < 4; ++j)
                sRed[wave][mi * 16 + lg * 4 + j] = ps[mi][j];  // row = (lane>>4)*4 + reg
    }
    __syncthreads();
    if (tid < BM) {
        float s = 0.f;
#pragma unroll
        for (int w = 0; w < 8; ++w) s += sRed[w][tid];
        u_out[m0 + tid] = s;
    }
}

// ---------------- k_post: softmax + top-4 + joint exact rescore + gather -------
__global__ __launch_bounds__(256)
void k_post(const float* __restrict__ u, const int* __restrict__ mask,
            const float* __restrict__ value, const float* __restrict__ W1,
            const float* __restrict__ w2q, const float* __restrict__ Vv,
            float* __restrict__ a_out, float* __restrict__ ctx_out) {
    __shared__ float sx[T_];
    __shared__ float rv[4];
    __shared__ int   ri[4];
    __shared__ float s_scalar;
    __shared__ int   s_cand[MAXC];
    __shared__ float s_score[MAXC];
    __shared__ __align__(16) float vrows[MAXC][D_];
    __shared__ int   s_t;

    const int b = blockIdx.x;
    const int tid = threadIdx.x;
    const int wave = tid >> 6, lane = tid & 63;

#pragma unroll
    for (int i = 0; i < 8; ++i) {
        const int t = tid * 8 + i;
        float x = u[b * T_ + t];
        if (mask[b * T_ + t] == 0) x = -1e20f;
        sx[t] = x;
    }
    __syncthreads();

    for (int r = 0; r < MAXC; ++r) {
        float v = -INFINITY; int vi = 0;
#pragma unroll
        for (int i = 0; i < 8; ++i) {
            const int t = tid * 8 + i;
            const float x = sx[t];
            if (x > v) { v = x; vi = t; }
        }
        for (int off = 32; off > 0; off >>= 1) {
            const float ov = __shfl_down(v, off, 64);
            const int   oi = __shfl_down(vi, off, 64);
            if (ov > v || (ov == v && oi < vi)) { v = ov; vi = oi; }
        }
        if (lane == 0) { rv[wave] = v; ri[wave] = vi; }
        __syncthreads();
        if (tid == 0) {
            float bv = rv[0]; int bi = ri[0];
            for (int w = 1; w < 4; ++w)
                if (rv[w] > bv || (rv[w] == bv && ri[w] < bi)) { bv = rv[w]; bi = ri[w]; }
            s_cand[r] = bi;
            if (r == 0) s_scalar = bv;
            sx[bi] = -INFINITY;
        }
        __syncthreads();
    }
    const float mx = s_scalar;

    float zloc = 0.f;
    float evals[8];
#pragma unroll
    for (int i = 0; i < 8; ++i) {
        const int t = tid * 8 + i;
        float x = u[b * T_ + t];
        if (mask[b * T_ + t] == 0) x = -1e20f;
        const float e = __expf(x - mx);
        evals[i] = e;
        zloc += e;
    }
    for (int off = 32; off > 0; off >>= 1) zloc += __shfl_down(zloc, off, 64);
    if (lane == 0) rv[wave] = zloc;
    __syncthreads();
    if (tid == 0) s_scalar = 1.0f / (rv[0] + rv[1] + rv[2] + rv[3]);
    __syncthreads();
    const float rz = s_scalar;
#pragma unroll
    for (int i = 0; i < 8; ++i) {
        const int t = tid * 8 + i;
        a_out[b * T_ + t] = evals[i] * rz;
    }

    // ---- joint exact fp32 rescore of the 4 candidates (one pass over W1) ----
#pragma unroll
    for (int ci = 0; ci < MAXC; ++ci) {
        const int t = s_cand[ci];
        vrows[ci][tid]       = value[((size_t)b * T_ + t) * D_ + tid];
        vrows[ci][tid + 256] = value[((size_t)b * T_ + t) * D_ + tid + 256];
    }
    __syncthreads();

    float dots[2][MAXC];
#pragma unroll
    for (int j = 0; j < 2; ++j)
#pragma unroll
        for (int ci = 0; ci < MAXC; ++ci) dots[j][ci] = 0.f;

    for (int d4 = 0; d4 < D_; d4 += 4) {
        floatx4 vr[MAXC];
#pragma unroll
        for (int ci = 0; ci < MAXC; ++ci)
            vr[ci] = *(const floatx4*)(&vrows[ci][d4]);
#pragma unroll
        for (int k = 0; k < 4; ++k) {
            const float w0 = W1[(size_t)(d4 + k) * U_ + tid];
            const float w1 = W1[(size_t)(d4 + k) * U_ + tid + 256];
#pragma unroll
            for (int ci = 0; ci < MAXC; ++ci) {
                dots[0][ci] = fmaf(vr[ci][k], w0, dots[0][ci]);
                dots[1][ci] = fmaf(vr[ci][k], w1, dots[1][ci]);
            }
        }
    }
    float sc[MAXC];
#pragma unroll
    for (int ci = 0; ci < MAXC; ++ci) {
        const float n0v = Vv[tid]       * tanhf(dots[0][ci] + w2q[b * U_ + tid]);
        const float n1v = Vv[tid + 256] * tanhf(dots[1][ci] + w2q[b * U_ + tid + 256]);
        sc[ci] = n0v + n1v;
    }
#pragma unroll
    for (int ci = 0; ci < MAXC; ++ci)
        for (int off = 32; off > 0; off >>= 1)
            sc[ci] += __shfl_down(sc[ci], off, 64);
    __syncthreads();
    if (lane == 0) {
#pragma unroll
        for (int ci = 0; ci < MAXC; ++ci)
            vrows[ci][wave] = sc[ci];
    }
    __syncthreads();
    if (tid == 0) {
#pragma unroll
        for (int ci = 0; ci < MAXC; ++ci) {
            const int t = s_cand[ci];
            float s = vrows[ci][0] + vrows[ci][1] + vrows[ci][2] + vrows[ci][3];
            if (mask[b * T_ + t] == 0) s = -1e20f;
            s_score[ci] = s;
        }
        float bv = s_score[0]; int bt = s_cand[0];
        for (int i = 1; i < MAXC; ++i) {
            if (s_score[i] > bv || (s_score[i] == bv && s_cand[i] < bt)) {
                bv = s_score[i]; bt = s_cand[i];
            }
        }
        s_t = bt;
    }
    __syncthreads();

    const int t = s_t;
    ctx_out[b * D_ + tid]       = value[((size_t)b * T_ + t) * D_ + tid];
    ctx_out[b * D_ + tid + 256] = value[((size_t)b * T_ + t) * D_ + tid + 256];
}

extern "C" void kernel_launch(void* const* d_in, const int* in_sizes, int n_in,
                              void* d_out, int out_size, void* d_ws, size_t ws_size,
                              hipStream_t stream) {
    const float* value = (const float*)d_in[0];   // [32,2048,512]
    const float* query = (const float*)d_in[1];   // [32,512]
    const int*   mask  = (const int*)d_in[2];     // [32,2048]
    const float* W1    = (const float*)d_in[3];   // [512,512]
    const float* W2    = (const float*)d_in[4];   // [512,512]
    const float* Vv    = (const float*)d_in[5];   // [512]

    char* ws = (char*)d_ws;
    _Float16* W1T  = (_Float16*)ws;                    // 524,288 B
    float*    w2q  = (float*)(ws + 524288);            //  65,536 B
    float*    u_ws = (float*)(ws + 524288 + 65536);    // 262,144 B

    float* ctx_out = (float*)d_out;              // [32,512]
    float* a_out   = (float*)d_out + B_ * D_;    // [32,2048]

    hipLaunchKernelGGL(k_prep,   dim3(192), dim3(256), 0, stream,
                       W1, query, W2, W1T, w2q);
    hipLaunchKernelGGL(k_gemm_u, dim3(M_ / BM), dim3(512), 0, stream,
                       value, W1T, w2q, Vv, u_ws);
    hipLaunchKernelGGL(k_post,   dim3(32), dim3(256), 0, stream,
                       u_ws, mask, value, W1, w2q, Vv, a_out, ctx_out);
}

// Round 4
// 292.392 us; speedup vs baseline: 1.0686x; 1.0464x over previous
//
#include <hip/hip_runtime.h>
#include <hip/hip_fp16.h>
#include <stdint.h>

// Problem constants
#define B_ 32
#define T_ 2048
#define D_ 512
#define U_ 512
#define M_ (B_ * T_)

// GEMM decomposition: N-split=2, 256 cols/block (reg-resident B), 32-row A chunks
#define NSPLIT 2
#define NCOLS 256
#define CHUNK 32
#define NCHUNK 8         // chunks per block
#define ROWS_PB 256      // rows per block
#define SAW 520          // sA row stride in halves (1040 B = 65*16, b128-aligned)
#define MAXC 4

typedef _Float16 half8   __attribute__((ext_vector_type(8)));
typedef float   floatx4  __attribute__((ext_vector_type(4)));
typedef float   floatx16 __attribute__((ext_vector_type(16)));

__device__ __forceinline__ float tanh_fast(float x) {
    float ax = fabsf(x);
    float e  = __expf(2.0f * ax);
    float t  = 1.0f - 2.0f / (e + 1.0f);
    return copysignf(t, x);
}

// ---------------- k_w2q: w2q[b][u] = query[b] @ W2, exact fp32 ----------------
// 128 blocks: b = bid>>2, 128-col n-chunk = bid&3
__global__ __launch_bounds__(256)
void k_w2q(const float* __restrict__ query, const float* __restrict__ W2,
           float* __restrict__ w2q) {
    __shared__ float sq[D_];
    __shared__ float part[128];
    const int tid = threadIdx.x;
    const int b  = blockIdx.x >> 2;
    const int nq = blockIdx.x & 3;
    sq[tid]       = query[b * D_ + tid];
    sq[tid + 256] = query[b * D_ + tid + 256];
    __syncthreads();
    const int n  = nq * 128 + (tid & 127);
    const int dh = tid >> 7;
    float acc = 0.f;
    const int d0 = dh * 256;
#pragma unroll 16
    for (int d = d0; d < d0 + 256; ++d)
        acc = fmaf(sq[d], W2[(size_t)d * U_ + n], acc);
    if (dh == 1) part[tid & 127] = acc;
    __syncthreads();
    if (dh == 0) w2q[b * U_ + n] = acc + part[tid];
}

// ---------------- k_gemm_u: streaming GEMM + tanh + V-dot -> u_part ----------------
// grid 512: slice = bx&1 (n-cols slice*256..+256), mblk = bx>>1 (256 rows).
// B slice lives in registers (128 VGPR/lane); loop streams A chunks only.
__global__ __launch_bounds__(512, 2)
void k_gemm_u(const float* __restrict__ value,
              const float* __restrict__ W1,     // [K=512][N=512] fp32 (original layout)
              const float* __restrict__ w2q,    // [32][512]
              const float* __restrict__ Vv,     // [512]
              float* __restrict__ u_part) {     // [2][65536]
    __shared__ __align__(16) _Float16 sA[2][CHUNK * SAW];  // 2 x 33,280 B
    __shared__ float sRed[2][8][CHUNK];                    // 2,048 B

    const int tid  = threadIdx.x;
    const int wave = tid >> 6;
    const int lane = tid & 63;
    const int l31  = lane & 31;
    const int hi   = lane >> 5;            // 0/1
    const int slice = blockIdx.x & 1;
    const int mblk  = blockIdx.x >> 1;
    const int mbase = mblk * ROWS_PB;
    const int b     = mbase >> 11;         // 256-row range stays within one batch

    // this wave's 32 n-columns; per-lane column:
    const int n_g = slice * NCOLS + wave * 32 + l31;
    const float w2 = w2q[b * U_ + n_g];
    const float vv = Vv[n_g];

    // ---- B preload (once): breg[s][j] = fp16(W1[(s*16 + hi*8 + j)*512 + n_g])
    // consecutive lanes -> consecutive n => coalesced 128B segments from L2.
    half8 breg[32];
#pragma unroll
    for (int s = 0; s < 32; ++s) {
        const int k0 = s * 16 + hi * 8;
        half8 h;
#pragma unroll
        for (int j = 0; j < 8; ++j)
            h[j] = (_Float16)W1[(size_t)(k0 + j) * U_ + n_g];
        breg[s] = h;
    }

    // ---- A chunk staging: instr i covers row i*8+wave, full 512 cols via 2 float4/lane
    floatx4 rA[8];

#define A_ISSUE(c)                                                              \
    {                                                                           \
        _Pragma("unroll")                                                       \
        for (int i = 0; i < 4; ++i) {                                           \
            const float* p = value +                                            \
                (size_t)(mbase + (c) * CHUNK + i * 8 + wave) * D_ + lane * 8;   \
            rA[i * 2]     = *(const floatx4*)p;                                 \
            rA[i * 2 + 1] = *(const floatx4*)(p + 4);                           \
        }                                                                       \
    }

#define A_STORE(buf)                                                            \
    {                                                                           \
        _Pragma("unroll")                                                       \
        for (int i = 0; i < 4; ++i) {                                           \
            half8 h;                                                            \
            _Pragma("unroll")                                                   \
            for (int j = 0; j < 4; ++j) {                                       \
                h[j]     = (_Float16)rA[i * 2][j];                              \
                h[4 + j] = (_Float16)rA[i * 2 + 1][j];                          \
            }                                                                   \
            *(half8*)(&sA[buf][(i * 8 + wave) * SAW + lane * 8]) = h;           \
        }                                                                       \
    }

    // prologue: stage chunk 0, load chunk 1 into regs
    A_ISSUE(0);
    A_STORE(0);
    A_ISSUE(1);
    __syncthreads();

    for (int c = 0; c < NCHUNK; ++c) {
        const int cur = c & 1;
        if (c + 1 < NCHUNK) A_STORE(cur ^ 1);   // regs(c+1) -> other LDS buf
        if (c + 2 < NCHUNK) A_ISSUE(c + 2);     // HBM loads, consumed next iter

        floatx16 acc;
#pragma unroll
        for (int r = 0; r < 16; ++r) acc[r] = 0.f;

#pragma unroll
        for (int s = 0; s < 32; ++s) {
            const half8 af = *(const half8*)(&sA[cur][l31 * SAW + s * 16 + hi * 8]);
            acc = __builtin_amdgcn_mfma_f32_32x32x16_f16(af, breg[s], acc, 0, 0, 0);
        }

        // epilogue: partial u over this wave's 32 cols
        float ps[16];
#pragma unroll
        for (int r = 0; r < 16; ++r) ps[r] = vv * tanh_fast(acc[r] + w2);
#pragma unroll
        for (int off = 1; off < 32; off <<= 1)
#pragma unroll
            for (int r = 0; r < 16; ++r) ps[r] += __shfl_xor(ps[r], off, 64);
        if (l31 == 0) {
#pragma unroll
            for (int r = 0; r < 16; ++r) {
                const int row = (r & 3) + 8 * (r >> 2) + 4 * hi;  // C/D row map
                sRed[cur][wave][row] = ps[r];
            }
        }
        __syncthreads();   // sRed[cur] ready; sA[cur^1] stores done; drains A-loads (BW-time)
        if (tid < CHUNK) {
            float ssum = 0.f;
#pragma unroll
            for (int w = 0; w < 8; ++w) ssum += sRed[cur][w][tid];
            u_part[(size_t)slice * M_ + mbase + c * CHUNK + tid] = ssum;
        }
    }
#undef A_ISSUE
#undef A_STORE
}

// ---------------- k_post: softmax + top-4 + joint exact rescore + gather -------
__global__ __launch_bounds__(256)
void k_post(const float* __restrict__ u_part, const int* __restrict__ mask,
            const float* __restrict__ value, const float* __restrict__ W1,
            const float* __restrict__ w2q, const float* __restrict__ Vv,
            float* __restrict__ a_out, float* __restrict__ ctx_out) {
    __shared__ float sx[T_];
    __shared__ float rv[4];
    __shared__ int   ri[4];
    __shared__ float s_scalar;
    __shared__ int   s_cand[MAXC];
    __shared__ float s_score[MAXC];
    __shared__ __align__(16) float vrows[MAXC][D_];
    __shared__ int   s_t;

    const int b = blockIdx.x;
    const int tid = threadIdx.x;
    const int wave = tid >> 6, lane = tid & 63;

#pragma unroll
    for (int i = 0; i < 8; ++i) {
        const int t = tid * 8 + i;
        float x = u_part[b * T_ + t] + u_part[M_ + b * T_ + t];
        if (mask[b * T_ + t] == 0) x = -1e20f;
        sx[t] = x;
    }
    __syncthreads();

    for (int r = 0; r < MAXC; ++r) {
        float v = -INFINITY; int vi = 0;
#pragma unroll
        for (int i = 0; i < 8; ++i) {
            const int t = tid * 8 + i;
            const float x = sx[t];
            if (x > v) { v = x; vi = t; }
        }
        for (int off = 32; off > 0; off >>= 1) {
            const float ov = __shfl_down(v, off, 64);
            const int   oi = __shfl_down(vi, off, 64);
            if (ov > v || (ov == v && oi < vi)) { v = ov; vi = oi; }
        }
        if (lane == 0) { rv[wave] = v; ri[wave] = vi; }
        __syncthreads();
        if (tid == 0) {
            float bv = rv[0]; int bi = ri[0];
            for (int w = 1; w < 4; ++w)
                if (rv[w] > bv || (rv[w] == bv && ri[w] < bi)) { bv = rv[w]; bi = ri[w]; }
            s_cand[r] = bi;
            if (r == 0) s_scalar = bv;
            sx[bi] = -INFINITY;
        }
        __syncthreads();
    }
    const float mx = s_scalar;

    float zloc = 0.f;
    float evals[8];
#pragma unroll
    for (int i = 0; i < 8; ++i) {
        const int t = tid * 8 + i;
        float x = u_part[b * T_ + t] + u_part[M_ + b * T_ + t];
        if (mask[b * T_ + t] == 0) x = -1e20f;
        const float e = __expf(x - mx);
        evals[i] = e;
        zloc += e;
    }
    for (int off = 32; off > 0; off >>= 1) zloc += __shfl_down(zloc, off, 64);
    if (lane == 0) rv[wave] = zloc;
    __syncthreads();
    if (tid == 0) s_scalar = 1.0f / (rv[0] + rv[1] + rv[2] + rv[3]);
    __syncthreads();
    const float rz = s_scalar;
#pragma unroll
    for (int i = 0; i < 8; ++i) {
        const int t = tid * 8 + i;
        a_out[b * T_ + t] = evals[i] * rz;
    }

    // ---- joint exact fp32 rescore of the 4 candidates (one pass over W1) ----
#pragma unroll
    for (int ci = 0; ci < MAXC; ++ci) {
        const int t = s_cand[ci];
        vrows[ci][tid]       = value[((size_t)b * T_ + t) * D_ + tid];
        vrows[ci][tid + 256] = value[((size_t)b * T_ + t) * D_ + tid + 256];
    }
    __syncthreads();

    float dots[2][MAXC];
#pragma unroll
    for (int j = 0; j < 2; ++j)
#pragma unroll
        for (int ci = 0; ci < MAXC; ++ci) dots[j][ci] = 0.f;

    for (int d4 = 0; d4 < D_; d4 += 4) {
        floatx4 vr[MAXC];
#pragma unroll
        for (int ci = 0; ci < MAXC; ++ci)
            vr[ci] = *(const floatx4*)(&vrows[ci][d4]);
#pragma unroll
        for (int k = 0; k < 4; ++k) {
            const float w0 = W1[(size_t)(d4 + k) * U_ + tid];
            const float w1 = W1[(size_t)(d4 + k) * U_ + tid + 256];
#pragma unroll
            for (int ci = 0; ci < MAXC; ++ci) {
                dots[0][ci] = fmaf(vr[ci][k], w0, dots[0][ci]);
                dots[1][ci] = fmaf(vr[ci][k], w1, dots[1][ci]);
            }
        }
    }
    float sc[MAXC];
#pragma unroll
    for (int ci = 0; ci < MAXC; ++ci) {
        const float n0v = Vv[tid]       * tanhf(dots[0][ci] + w2q[b * U_ + tid]);
        const float n1v = Vv[tid + 256] * tanhf(dots[1][ci] + w2q[b * U_ + tid + 256]);
        sc[ci] = n0v + n1v;
    }
#pragma unroll
    for (int ci = 0; ci < MAXC; ++ci)
        for (int off = 32; off > 0; off >>= 1)
            sc[ci] += __shfl_down(sc[ci], off, 64);
    __syncthreads();
    if (lane == 0) {
#pragma unroll
        for (int ci = 0; ci < MAXC; ++ci)
            vrows[ci][wave] = sc[ci];
    }
    __syncthreads();
    if (tid == 0) {
#pragma unroll
        for (int ci = 0; ci < MAXC; ++ci) {
            const int t = s_cand[ci];
            float s = vrows[ci][0] + vrows[ci][1] + vrows[ci][2] + vrows[ci][3];
            if (mask[b * T_ + t] == 0) s = -1e20f;
            s_score[ci] = s;
        }
        float bv = s_score[0]; int bt = s_cand[0];
        for (int i = 1; i < MAXC; ++i) {
            if (s_score[i] > bv || (s_score[i] == bv && s_cand[i] < bt)) {
                bv = s_score[i]; bt = s_cand[i];
            }
        }
        s_t = bt;
    }
    __syncthreads();

    const int t = s_t;
    ctx_out[b * D_ + tid]       = value[((size_t)b * T_ + t) * D_ + tid];
    ctx_out[b * D_ + tid + 256] = value[((size_t)b * T_ + t) * D_ + tid + 256];
}

extern "C" void kernel_launch(void* const* d_in, const int* in_sizes, int n_in,
                              void* d_out, int out_size, void* d_ws, size_t ws_size,
                              hipStream_t stream) {
    const float* value = (const float*)d_in[0];   // [32,2048,512]
    const float* query = (const float*)d_in[1];   // [32,512]
    const int*   mask  = (const int*)d_in[2];     // [32,2048]
    const float* W1    = (const float*)d_in[3];   // [512,512]
    const float* W2    = (const float*)d_in[4];   // [512,512]
    const float* Vv    = (const float*)d_in[5];   // [512]

    char* ws = (char*)d_ws;
    float* w2q    = (float*)ws;                   //  65,536 B
    float* u_part = (float*)(ws + 65536);         // 524,288 B (2 x 65536 floats)

    float* ctx_out = (float*)d_out;              // [32,512]
    float* a_out   = (float*)d_out + B_ * D_;    // [32,2048]

    hipLaunchKernelGGL(k_w2q,    dim3(128), dim3(256), 0, stream, query, W2, w2q);
    hipLaunchKernelGGL(k_gemm_u, dim3(NSPLIT * (M_ / ROWS_PB)), dim3(512), 0, stream,
                       value, W1, w2q, Vv, u_part);
    hipLaunchKernelGGL(k_post,   dim3(32), dim3(256), 0, stream,
                       u_part, mask, value, W1, w2q, Vv, a_out, ctx_out);
}